// Round 1
// baseline (261.696 us; speedup 1.0000x reference)
//
#include <hip/hip_runtime.h>
#include <math.h>

// AFM: one block per batch sample. 256 threads (4 waves).
// Sizes fixed by the reference.
constexpr int kT = 100;     // NUM_TREES
constexpr int kP = 4950;    // T*(T-1)/2 pairs
constexpr int kD = 32;      // DIM
constexpr int kA = 16;      // ATT
constexpr int kES = 34;     // LDS row stride for e (float2-aligned, limits bank aliasing)

// LDS union buffer:
//   phase A: sh_e[100*34]=3400 floats  +  sh_logit[4950] at offset 3400 -> 8350
//   phase B: pooled staging, 256 rows * stride 33 = 8448 floats
// union size = 8448 floats = 33792 B  (+ small extras) -> 4 blocks/CU on 160KB LDS

__global__ __launch_bounds__(256, 4)
void afm_kernel(const int* __restrict__ x,
                const float* __restrict__ Emb,
                const float* __restrict__ W,    // (32,16) row-major
                const float* __restrict__ bb,   // (16,)
                const float* __restrict__ h,    // (16,)
                const float* __restrict__ W1,   // (32,16)
                const float* __restrict__ b1,   // (16,)
                const float* __restrict__ W2,   // (16,8)
                const float* __restrict__ b2,   // (8,)
                const float* __restrict__ Wf,   // (8,)
                const float* __restrict__ bf,   // (1,)
                float* __restrict__ out)        // (1024,)
{
    __shared__ float buf[8448];
    __shared__ float red[8];
    __shared__ float sh_pooled[kD];
    __shared__ float sh_o1[kA];
    __shared__ float sh_o2[8];

    float* sh_e = buf;              // stride kES, 100 rows
    float* sh_logit = buf + 3400;   // kP floats

    const int tid = threadIdx.x;
    const int b = blockIdx.x;
    const int lane = tid & 63;
    const int wv = tid >> 6;

    // ---- gather embeddings: e[row][d] = Emb[x[b][row]][d] ----
    const int* xb = x + b * kT;
    for (int i = tid; i < kT * 16; i += 256) {
        const int row = i >> 4, c = i & 15;           // 16 float2 chunks per row
        const int v = xb[row];
        const float2 val = ((const float2*)Emb)[v * 16 + c];
        ((float2*)sh_e)[row * (kES / 2) + c] = val;
    }
    __syncthreads();

    // ---- pass 1: per-pair attention logits ----
    for (int p = tid; p < kP; p += 256) {
        // closed-form row from p: base(r) = r*(199-r)/2, perfect square at bounds
        const float t = 39601.0f - 8.0f * (float)p;
        int r = (int)((199.0f - sqrtf(t)) * 0.5f);
        if (r < 0) r = 0;
        if (r > 98) r = 98;
        int base = r * 99 - ((r * (r - 1)) >> 1);
        while (base > p) { --r; base = r * 99 - ((r * (r - 1)) >> 1); }
        while (p - base >= (99 - r)) { base += (99 - r); ++r; }
        const int c = r + 1 + (p - base);

        const float2* er = (const float2*)(sh_e + r * kES);
        const float2* ec = (const float2*)(sh_e + c * kES);

        float s_acc[kA];
#pragma unroll
        for (int a = 0; a < kA; ++a) s_acc[a] = bb[a];

#pragma unroll
        for (int dc = 0; dc < kD / 2; ++dc) {
            const float2 u = er[dc];
            const float2 v = ec[dc];
            const float hb0 = u.x * v.x;
            const float hb1 = u.y * v.y;
#pragma unroll
            for (int a = 0; a < kA; ++a) {
                // W indices are wave-uniform & compile-time -> expect s_load
                s_acc[a] = fmaf(hb1, W[(2 * dc + 1) * kA + a],
                           fmaf(hb0, W[(2 * dc) * kA + a], s_acc[a]));
            }
        }
        float logit = 0.0f;
#pragma unroll
        for (int a = 0; a < kA; ++a)
            logit = fmaf(fmaxf(s_acc[a], 0.0f), h[a], logit);
        sh_logit[p] = logit;
    }
    __syncthreads();

    // ---- block softmax over kP logits ----
    float mx = -1e30f;
    for (int p = tid; p < kP; p += 256) mx = fmaxf(mx, sh_logit[p]);
#pragma unroll
    for (int off = 1; off < 64; off <<= 1) mx = fmaxf(mx, __shfl_xor(mx, off, 64));
    if (lane == 0) red[wv] = mx;
    __syncthreads();
    mx = fmaxf(fmaxf(red[0], red[1]), fmaxf(red[2], red[3]));

    float lsum = 0.0f;
    for (int p = tid; p < kP; p += 256) {
        const float v = __expf(sh_logit[p] - mx);
        sh_logit[p] = v;          // store unnormalized att in place
        lsum += v;
    }
#pragma unroll
    for (int off = 1; off < 64; off <<= 1) lsum += __shfl_xor(lsum, off, 64);
    if (lane == 0) red[4 + wv] = lsum;
    __syncthreads();
    const float invS = 1.0f / (red[4] + red[5] + red[6] + red[7]);

    // ---- pass 2: attention-weighted pooling ----
    float2 pool[kD / 2];
#pragma unroll
    for (int dc = 0; dc < kD / 2; ++dc) pool[dc] = make_float2(0.0f, 0.0f);

    for (int p = tid; p < kP; p += 256) {
        const float t = 39601.0f - 8.0f * (float)p;
        int r = (int)((199.0f - sqrtf(t)) * 0.5f);
        if (r < 0) r = 0;
        if (r > 98) r = 98;
        int base = r * 99 - ((r * (r - 1)) >> 1);
        while (base > p) { --r; base = r * 99 - ((r * (r - 1)) >> 1); }
        while (p - base >= (99 - r)) { base += (99 - r); ++r; }
        const int c = r + 1 + (p - base);

        const float att = sh_logit[p];
        const float2* er = (const float2*)(sh_e + r * kES);
        const float2* ec = (const float2*)(sh_e + c * kES);
#pragma unroll
        for (int dc = 0; dc < kD / 2; ++dc) {
            const float2 u = er[dc];
            const float2 v = ec[dc];
            pool[dc].x = fmaf(att, u.x * v.x, pool[dc].x);
            pool[dc].y = fmaf(att, u.y * v.y, pool[dc].y);
        }
    }
    __syncthreads();   // everyone done reading sh_e / sh_logit

    // stage per-thread pooled vectors (stride 33 -> conflict-free columns)
#pragma unroll
    for (int dc = 0; dc < kD / 2; ++dc) {
        buf[tid * 33 + 2 * dc] = pool[dc].x;
        buf[tid * 33 + 2 * dc + 1] = pool[dc].y;
    }
    __syncthreads();

    if (tid < kD) {
        float s = 0.0f;
        for (int t2 = 0; t2 < 256; ++t2) s += buf[t2 * 33 + tid];
        sh_pooled[tid] = s * invS;
    }
    __syncthreads();

    // ---- MLP head ----
    if (tid < kA) {
        float o = b1[tid];
#pragma unroll
        for (int d = 0; d < kD; ++d) o = fmaf(sh_pooled[d], W1[d * kA + tid], o);
        sh_o1[tid] = fmaxf(o, 0.0f);
    }
    __syncthreads();
    if (tid < 8) {
        float o = b2[tid];
#pragma unroll
        for (int a = 0; a < kA; ++a) o = fmaf(sh_o1[a], W2[a * 8 + tid], o);
        sh_o2[tid] = fmaxf(o, 0.0f);
    }
    __syncthreads();
    if (tid == 0) {
        float z = bf[0];
#pragma unroll
        for (int j = 0; j < 8; ++j) z = fmaf(sh_o2[j], Wf[j], z);
        out[b] = 1.0f / (1.0f + __expf(-z));
    }
}

extern "C" void kernel_launch(void* const* d_in, const int* in_sizes, int n_in,
                              void* d_out, int out_size, void* d_ws, size_t ws_size,
                              hipStream_t stream) {
    const int*   x   = (const int*)d_in[0];
    const float* Emb = (const float*)d_in[1];
    const float* W   = (const float*)d_in[2];
    const float* bb  = (const float*)d_in[3];
    const float* h   = (const float*)d_in[4];
    const float* W1  = (const float*)d_in[5];
    const float* b1  = (const float*)d_in[6];
    const float* W2  = (const float*)d_in[7];
    const float* b2  = (const float*)d_in[8];
    const float* Wf  = (const float*)d_in[9];
    const float* bf  = (const float*)d_in[10];
    float* out = (float*)d_out;

    afm_kernel<<<1024, 256, 0, stream>>>(x, Emb, W, bb, h, W1, b1, W2, b2, Wf, bf, out);
}

// Round 3
// 151.620 us; speedup vs baseline: 1.7260x; 1.7260x over previous
//
#include <hip/hip_runtime.h>
#include <math.h>

// AFM on MFMA: one block = one sample, 256 threads (4 waves).
// S-GEMM: S^T(16a x 4950p) = W^T(16x32) @ HB^T(32x4950) via mfma_f32_16x16x32_f16,
// one MFMA per 16-pair tile (K=32 == DIM exactly, no K loop).
constexpr int kT = 100;
constexpr int kP = 4950;
constexpr int kD = 32;
constexpr int kA = 16;
constexpr int kES = 36;          // e row stride in floats: 144B, 16B-aligned, even bank spread
constexpr int kTiles = (kP + 15) / 16;   // 310

typedef float  float4v  __attribute__((ext_vector_type(4)));
typedef __fp16   fp16x2 __attribute__((ext_vector_type(2)));   // cvt_pkrtz result type
typedef _Float16 half8v __attribute__((ext_vector_type(8)));   // MFMA operand type

// LDS plan (floats):
//   sh_e    : [0, 3600)            e fp32, 100 rows x stride 36
//   sh_pair : [3600, 6075)         4950 ushorts (r<<8|c)
//   sh_logit: [6075, 11025)        4950 logits -> exp(att) in place
//   staging for pooled reduce aliases [0, 4256) AFTER pass2 (e+pair dead then)
__global__ __launch_bounds__(256, 3)
void afm_kernel(const int* __restrict__ x,
                const float* __restrict__ Emb,
                const float* __restrict__ W,    // (32,16)
                const float* __restrict__ bb,   // (16,)
                const float* __restrict__ h,    // (16,)
                const float* __restrict__ W1,   // (32,16)
                const float* __restrict__ b1,   // (16,)
                const float* __restrict__ W2,   // (16,8)
                const float* __restrict__ b2,   // (8,)
                const float* __restrict__ Wf,   // (8,)
                const float* __restrict__ bf,   // (1,)
                float* __restrict__ out)        // (1024,)
{
    __shared__ __align__(16) float lds[11025];
    __shared__ float red[8];
    __shared__ float sh_pooled[kD];
    __shared__ float sh_o1[kA];
    __shared__ float sh_o2[8];

    float* sh_e = lds;
    unsigned short* sh_pair = (unsigned short*)(lds + 3600);
    float* sh_logit = lds + 6075;

    const int tid  = threadIdx.x;
    const int b    = blockIdx.x;
    const int lane = tid & 63;
    const int wv   = tid >> 6;
    const int quad = lane >> 4;
    const int l15  = lane & 15;

    // ---- gather embeddings (float4) + pair table ----
    const int* xb = x + b * kT;
    for (int i = tid; i < kT * 8; i += 256) {
        const int row = i >> 3, c4 = i & 7;
        const int v = xb[row];
        const float4 val = ((const float4*)Emb)[v * 8 + c4];
        ((float4*)(sh_e + row * kES))[c4] = val;
    }
    for (int p = tid; p < kP; p += 256) {
        const float tq = 39601.0f - 8.0f * (float)p;
        int r = (int)((199.0f - sqrtf(tq)) * 0.5f);
        if (r < 0) r = 0;
        if (r > 98) r = 98;
        int base = r * 99 - ((r * (r - 1)) >> 1);
        while (base > p) { --r; base = r * 99 - ((r * (r - 1)) >> 1); }
        while (p - base >= (99 - r)) { base += (99 - r); ++r; }
        const int c = r + 1 + (p - base);
        sh_pair[p] = (unsigned short)((r << 8) | c);
    }

    // ---- A-frag: W^T, lane holds W[k0+j][a=l15], j=0..7; plus h,b slices ----
    const int k0 = quad * 8;
    union { fp16x2 h2[4]; half8v h8; } wa;
#pragma unroll
    for (int j = 0; j < 4; ++j)
        wa.h2[j] = __builtin_amdgcn_cvt_pkrtz(W[(k0 + 2 * j) * kA + l15],
                                              W[(k0 + 2 * j + 1) * kA + l15]);
    float h_reg[4], b_reg[4];
#pragma unroll
    for (int rg = 0; rg < 4; ++rg) {
        h_reg[rg] = h[quad * 4 + rg];
        b_reg[rg] = bb[quad * 4 + rg];
    }
    __syncthreads();

    // ---- phase S: one MFMA per 16-pair tile ----
#pragma unroll 2
    for (int t = wv; t < kTiles; t += 4) {
        const int p_raw = t * 16 + l15;
        const int p = p_raw < kP ? p_raw : kP - 1;
        const unsigned short pr = sh_pair[p];
        const int r = pr >> 8, c = pr & 255;

        const float4* er = (const float4*)(sh_e + r * kES + k0);
        const float4* ec = (const float4*)(sh_e + c * kES + k0);
        const float4 u0 = er[0], u1 = er[1];
        const float4 v0 = ec[0], v1 = ec[1];

        union { fp16x2 h2[4]; half8v h8; } hb;
        hb.h2[0] = __builtin_amdgcn_cvt_pkrtz(u0.x * v0.x, u0.y * v0.y);
        hb.h2[1] = __builtin_amdgcn_cvt_pkrtz(u0.z * v0.z, u0.w * v0.w);
        hb.h2[2] = __builtin_amdgcn_cvt_pkrtz(u1.x * v1.x, u1.y * v1.y);
        hb.h2[3] = __builtin_amdgcn_cvt_pkrtz(u1.z * v1.z, u1.w * v1.w);

        float4v acc = {0.0f, 0.0f, 0.0f, 0.0f};
        acc = __builtin_amdgcn_mfma_f32_16x16x32_f16(wa.h8, hb.h8, acc, 0, 0, 0);

        // lane holds S^T[a=quad*4+rg][p=l15]; logit_p = sum_a relu(s+b)*h
        float part = 0.0f;
#pragma unroll
        for (int rg = 0; rg < 4; ++rg) {
            const float s = fmaxf(acc[rg] + b_reg[rg], 0.0f);
            part = fmaf(s, h_reg[rg], part);
        }
        part += __shfl_xor(part, 16, 64);
        part += __shfl_xor(part, 32, 64);
        if (quad == 0 && p_raw < kP) sh_logit[p_raw] = part;
    }
    __syncthreads();

    // ---- block softmax over kP logits ----
    float mx = -1e30f;
    for (int p = tid; p < kP; p += 256) mx = fmaxf(mx, sh_logit[p]);
#pragma unroll
    for (int off = 1; off < 64; off <<= 1) mx = fmaxf(mx, __shfl_xor(mx, off, 64));
    if (lane == 0) red[wv] = mx;
    __syncthreads();
    mx = fmaxf(fmaxf(red[0], red[1]), fmaxf(red[2], red[3]));

    float lsum = 0.0f;
    for (int p = tid; p < kP; p += 256) {
        const float v = __expf(sh_logit[p] - mx);
        sh_logit[p] = v;
        lsum += v;
    }
#pragma unroll
    for (int off = 1; off < 64; off <<= 1) lsum += __shfl_xor(lsum, off, 64);
    if (lane == 0) red[4 + wv] = lsum;
    __syncthreads();
    const float invS = 1.0f / (red[4] + red[5] + red[6] + red[7]);

    // ---- pass 2: attention-weighted pooling (fp32, float4) ----
    float4 pool[8];
#pragma unroll
    for (int dq = 0; dq < 8; ++dq) pool[dq] = make_float4(0.f, 0.f, 0.f, 0.f);

    for (int p = tid; p < kP; p += 256) {
        const unsigned short pr = sh_pair[p];
        const int r = pr >> 8, c = pr & 255;
        const float att = sh_logit[p];
        const float4* er = (const float4*)(sh_e + r * kES);
        const float4* ec = (const float4*)(sh_e + c * kES);
#pragma unroll
        for (int dq = 0; dq < 8; ++dq) {
            const float4 u = er[dq];
            const float4 v = ec[dq];
            pool[dq].x = fmaf(att * u.x, v.x, pool[dq].x);
            pool[dq].y = fmaf(att * u.y, v.y, pool[dq].y);
            pool[dq].z = fmaf(att * u.z, v.z, pool[dq].z);
            pool[dq].w = fmaf(att * u.w, v.w, pool[dq].w);
        }
    }
    __syncthreads();   // e, pair, att all dead after this point (att consumed)

    // ---- pooled reduce: two 128-thread staging batches over lds[0,4256) ----
    float part_sum = 0.0f;
    if (tid < 128) {
#pragma unroll
        for (int dq = 0; dq < 8; ++dq) {
            lds[tid * 33 + 4 * dq + 0] = pool[dq].x;
            lds[tid * 33 + 4 * dq + 1] = pool[dq].y;
            lds[tid * 33 + 4 * dq + 2] = pool[dq].z;
            lds[tid * 33 + 4 * dq + 3] = pool[dq].w;
        }
    }
    __syncthreads();
    if (tid < kD) {
        for (int t2 = 0; t2 < 128; ++t2) part_sum += lds[t2 * 33 + tid];
    }
    __syncthreads();
    if (tid >= 128) {
        const int t3 = tid - 128;
#pragma unroll
        for (int dq = 0; dq < 8; ++dq) {
            lds[t3 * 33 + 4 * dq + 0] = pool[dq].x;
            lds[t3 * 33 + 4 * dq + 1] = pool[dq].y;
            lds[t3 * 33 + 4 * dq + 2] = pool[dq].z;
            lds[t3 * 33 + 4 * dq + 3] = pool[dq].w;
        }
    }
    __syncthreads();
    if (tid < kD) {
        for (int t2 = 0; t2 < 128; ++t2) part_sum += lds[t2 * 33 + tid];
        sh_pooled[tid] = part_sum * invS;
    }
    __syncthreads();

    // ---- MLP head ----
    if (tid < kA) {
        float o = b1[tid];
#pragma unroll
        for (int d = 0; d < kD; ++d) o = fmaf(sh_pooled[d], W1[d * kA + tid], o);
        sh_o1[tid] = fmaxf(o, 0.0f);
    }
    __syncthreads();
    if (tid < 8) {
        float o = b2[tid];
#pragma unroll
        for (int a = 0; a < kA; ++a) o = fmaf(sh_o1[a], W2[a * 8 + tid], o);
        sh_o2[tid] = fmaxf(o, 0.0f);
    }
    __syncthreads();
    if (tid == 0) {
        float z = bf[0];
#pragma unroll
        for (int j = 0; j < 8; ++j) z = fmaf(sh_o2[j], Wf[j], z);
        out[b] = 1.0f / (1.0f + __expf(-z));
    }
}

extern "C" void kernel_launch(void* const* d_in, const int* in_sizes, int n_in,
                              void* d_out, int out_size, void* d_ws, size_t ws_size,
                              hipStream_t stream) {
    const int*   x   = (const int*)d_in[0];
    const float* Emb = (const float*)d_in[1];
    const float* W   = (const float*)d_in[2];
    const float* bb  = (const float*)d_in[3];
    const float* h   = (const float*)d_in[4];
    const float* W1  = (const float*)d_in[5];
    const float* b1  = (const float*)d_in[6];
    const float* W2  = (const float*)d_in[7];
    const float* b2  = (const float*)d_in[8];
    const float* Wf  = (const float*)d_in[9];
    const float* bf  = (const float*)d_in[10];
    float* out = (float*)d_out;

    afm_kernel<<<1024, 256, 0, stream>>>(x, Emb, W, bb, h, W1, b1, W2, b2, Wf, bf, out);
}

// Round 4
// 115.636 us; speedup vs baseline: 2.2631x; 1.3112x over previous
//
#include <hip/hip_runtime.h>
#include <math.h>

// AFM fused single-pass: one block = one sample, 256 threads (4 waves).
// Per 16-pair tile: one mfma_f32_16x16x32_f16 (S^T = W^T @ HB^T), quad-butterfly
// -> full logit per lane, w = exp(logit) (no-max softmax: |logit| < ~0.5),
// pool[8 dims] += w * hb (hb already in registers). No pass 2, no logit array.
constexpr int kT = 100;
constexpr int kP = 4950;
constexpr int kD = 32;
constexpr int kA = 16;
constexpr int kESH = 40;                 // e row stride in halfs (80B, 16B-aligned)
constexpr int kTiles = (kP + 15) / 16;   // 310
constexpr int kTblPad = 4960;            // pair table padded to 16B multiple

typedef float    float4v __attribute__((ext_vector_type(4)));
typedef __fp16   fp16x2  __attribute__((ext_vector_type(2)));
typedef __fp16   half4   __attribute__((ext_vector_type(4)));
typedef __fp16   half8   __attribute__((ext_vector_type(8)));
typedef _Float16 half8v  __attribute__((ext_vector_type(8)));

__device__ __forceinline__ void pair_decode(int p, int& r, int& c) {
    const float tq = 39601.0f - 8.0f * (float)p;
    r = (int)((199.0f - sqrtf(tq)) * 0.5f);
    if (r < 0) r = 0;
    if (r > 98) r = 98;
    int base = r * 99 - ((r * (r - 1)) >> 1);
    while (base > p) { --r; base = r * 99 - ((r * (r - 1)) >> 1); }
    while (p - base >= (99 - r)) { base += (99 - r); ++r; }
    c = r + 1 + (p - base);
}

__global__ void pair_init(unsigned short* __restrict__ tbl) {
    const int p = blockIdx.x * 256 + threadIdx.x;
    if (p < kTblPad) {
        int r, c;
        pair_decode(p < kP ? p : kP - 1, r, c);
        tbl[p] = (unsigned short)((r << 8) | c);
    }
}

// LDS: she 100*40 halfs = 8000 B | sh_pair 4960 u16 = 9920 B  (total 17920)
// stg (256*9 floats = 9216 B) aliases the same region after the main loop.
template <bool USE_TBL>
__global__ __launch_bounds__(256, 4)
void afm_kernel(const int* __restrict__ x,
                const float* __restrict__ Emb,
                const float* __restrict__ W,    // (32,16)
                const float* __restrict__ bb,   // (16,)
                const float* __restrict__ h,    // (16,)
                const float* __restrict__ W1,   // (32,16)
                const float* __restrict__ b1,   // (16,)
                const float* __restrict__ W2,   // (16,8)
                const float* __restrict__ b2,   // (8,)
                const float* __restrict__ Wf,   // (8,)
                const float* __restrict__ bf,   // (1,)
                const unsigned short* __restrict__ tbl,
                float* __restrict__ out)        // (1024,)
{
    __shared__ __align__(16) unsigned char smem[17920];
    __shared__ float red[4];
    __shared__ float sh_pooled[kD];
    __shared__ float sh_o1[kA];
    __shared__ float sh_o2[8];

    __fp16* she = (__fp16*)smem;
    unsigned short* sh_pair = (unsigned short*)(smem + 8000);

    const int tid  = threadIdx.x;
    const int b    = blockIdx.x;
    const int lane = tid & 63;
    const int wv   = tid >> 6;
    const int quad = lane >> 4;
    const int l15  = lane & 15;
    const int k0   = quad * 8;      // this quad's K slice (dims k0..k0+7)

    // ---- gather embeddings -> f16 LDS ----
    const int* xb = x + b * kT;
    for (int i = tid; i < kT * 8; i += 256) {
        const int row = i >> 3, c4 = i & 7;
        const int v = xb[row];
        const float4 val = ((const float4*)Emb)[v * 8 + c4];
        union { fp16x2 h2[2]; half4 h4; } tmp;
        tmp.h2[0] = __builtin_amdgcn_cvt_pkrtz(val.x, val.y);
        tmp.h2[1] = __builtin_amdgcn_cvt_pkrtz(val.z, val.w);
        *(half4*)(she + row * kESH + c4 * 4) = tmp.h4;
    }
    // ---- pair table: coalesced load from d_ws, or in-block decode fallback ----
    if (USE_TBL) {
        const uint4* t4 = (const uint4*)tbl;
        for (int i = tid; i < kTblPad / 8; i += 256)   // 620 uint4
            ((uint4*)sh_pair)[i] = t4[i];
    } else {
        for (int p = tid; p < kP; p += 256) {
            int r, c;
            pair_decode(p, r, c);
            sh_pair[p] = (unsigned short)((r << 8) | c);
        }
    }

    // ---- A-frag: W^T in f16 (lane holds W[k0+j][a=l15]) + h,b slices ----
    union { fp16x2 h2[4]; half8v h8; } wa;
#pragma unroll
    for (int j = 0; j < 4; ++j)
        wa.h2[j] = __builtin_amdgcn_cvt_pkrtz(W[(k0 + 2 * j) * kA + l15],
                                              W[(k0 + 2 * j + 1) * kA + l15]);
    float h_reg[4], b_reg[4];
#pragma unroll
    for (int rg = 0; rg < 4; ++rg) {
        h_reg[rg] = h[quad * 4 + rg];
        b_reg[rg] = bb[quad * 4 + rg];
    }
    __syncthreads();

    // ---- fused main loop ----
    float pool[8];
#pragma unroll
    for (int j = 0; j < 8; ++j) pool[j] = 0.0f;
    float lsum = 0.0f;

#pragma unroll 2
    for (int t = wv; t < kTiles; t += 4) {
        const int p_raw = t * 16 + l15;
        const int p = p_raw < kP ? p_raw : kP - 1;
        const unsigned pr = sh_pair[p];
        const int roff = (int)(pr >> 8) * kESH;
        const int coff = (int)(pr & 255) * kESH;

        const half8 er = *(const half8*)(she + roff + k0);
        const half8 ec = *(const half8*)(she + coff + k0);
        union { half8 fp; half8v mf; } hb;
        hb.fp = er * ec;                       // 4x v_pk_mul_f16

        float4v acc = {0.0f, 0.0f, 0.0f, 0.0f};
        acc = __builtin_amdgcn_mfma_f32_16x16x32_f16(wa.h8, hb.mf, acc, 0, 0, 0);

        // lane holds S^T[a=quad*4+rg][p=l15]
        float part = 0.0f;
#pragma unroll
        for (int rg = 0; rg < 4; ++rg) {
            const float s = fmaxf(acc[rg] + b_reg[rg], 0.0f);
            part = fmaf(s, h_reg[rg], part);
        }
        part += __shfl_xor(part, 16, 64);      // full logit in every quad
        part += __shfl_xor(part, 32, 64);

        const float w = (p_raw < kP) ? __expf(part) : 0.0f;
        lsum += w;
#pragma unroll
        for (int j = 0; j < 8; ++j)
            pool[j] = fmaf(w, (float)hb.fp[j], pool[j]);
    }

    // ---- reduce l (quads duplicate w -> /4) ----
#pragma unroll
    for (int off = 1; off < 64; off <<= 1) lsum += __shfl_xor(lsum, off, 64);
    if (lane == 0) red[wv] = lsum;

    __syncthreads();                 // main-loop LDS reads done; smem reusable
    float* stg = (float*)smem;       // 256 * 9 floats = 9216 B
#pragma unroll
    for (int j = 0; j < 8; ++j) stg[tid * 9 + j] = pool[j];
    __syncthreads();

    if (tid < kD) {
        const float invS = 4.0f / (red[0] + red[1] + red[2] + red[3]);
        const int q = tid >> 3, j = tid & 7;
        float s = 0.0f;
        for (int w4 = 0; w4 < 4; ++w4)
            for (int l = 0; l < 16; ++l)
                s += stg[(w4 * 64 + q * 16 + l) * 9 + j];
        sh_pooled[tid] = s * invS;
    }
    __syncthreads();

    // ---- MLP head ----
    if (tid < kA) {
        float o = b1[tid];
#pragma unroll
        for (int d = 0; d < kD; ++d) o = fmaf(sh_pooled[d], W1[d * kA + tid], o);
        sh_o1[tid] = fmaxf(o, 0.0f);
    }
    __syncthreads();
    if (tid < 8) {
        float o = b2[tid];
#pragma unroll
        for (int a = 0; a < kA; ++a) o = fmaf(sh_o1[a], W2[a * 8 + tid], o);
        sh_o2[tid] = fmaxf(o, 0.0f);
    }
    __syncthreads();
    if (tid == 0) {
        float z = bf[0];
#pragma unroll
        for (int j = 0; j < 8; ++j) z = fmaf(sh_o2[j], Wf[j], z);
        out[b] = 1.0f / (1.0f + __expf(-z));
    }
}

extern "C" void kernel_launch(void* const* d_in, const int* in_sizes, int n_in,
                              void* d_out, int out_size, void* d_ws, size_t ws_size,
                              hipStream_t stream) {
    const int*   x   = (const int*)d_in[0];
    const float* Emb = (const float*)d_in[1];
    const float* W   = (const float*)d_in[2];
    const float* bb  = (const float*)d_in[3];
    const float* h   = (const float*)d_in[4];
    const float* W1  = (const float*)d_in[5];
    const float* b1  = (const float*)d_in[6];
    const float* W2  = (const float*)d_in[7];
    const float* b2  = (const float*)d_in[8];
    const float* Wf  = (const float*)d_in[9];
    const float* bf  = (const float*)d_in[10];
    float* out = (float*)d_out;

    if (ws_size >= (size_t)(kTblPad * 2)) {
        unsigned short* tbl = (unsigned short*)d_ws;
        pair_init<<<(kTblPad + 255) / 256, 256, 0, stream>>>(tbl);
        afm_kernel<true><<<1024, 256, 0, stream>>>(x, Emb, W, bb, h, W1, b1, W2, b2,
                                                   Wf, bf, tbl, out);
    } else {
        afm_kernel<false><<<1024, 256, 0, stream>>>(x, Emb, W, bb, h, W1, b1, W2, b2,
                                                    Wf, bf, nullptr, out);
    }
}

// Round 5
// 113.707 us; speedup vs baseline: 2.3015x; 1.0170x over previous
//
#include <hip/hip_runtime.h>
#include <math.h>

// AFM fused single-pass: one block = one sample, 512 threads (8 waves).
// Per 16-pair tile: one mfma_f32_16x16x32_f16 (S^T = W^T @ HB^T, C preloaded
// with bias), quad-butterfly -> full logit per lane, w = exp(logit) (no-max
// softmax: |logit| < ~0.5 by construction), pool[8 dims] += w * hb in-register.
constexpr int kT = 100;
constexpr int kP = 4950;
constexpr int kD = 32;
constexpr int kA = 16;
constexpr int kESH = 40;                 // e row stride in halfs (80B, 16B-aligned)
constexpr int kTiles = (kP + 15) / 16;   // 310
constexpr int kTblPad = 4960;            // pair table padded to 16B multiple
constexpr int kNT = 512;                 // threads per block (8 waves)

typedef float    float4v __attribute__((ext_vector_type(4)));
typedef __fp16   fp16x2  __attribute__((ext_vector_type(2)));
typedef __fp16   half4   __attribute__((ext_vector_type(4)));
typedef __fp16   half8   __attribute__((ext_vector_type(8)));
typedef _Float16 half8v  __attribute__((ext_vector_type(8)));

__device__ __forceinline__ void pair_decode(int p, int& r, int& c) {
    const float tq = 39601.0f - 8.0f * (float)p;
    r = (int)((199.0f - sqrtf(tq)) * 0.5f);
    if (r < 0) r = 0;
    if (r > 98) r = 98;
    int base = r * 99 - ((r * (r - 1)) >> 1);
    while (base > p) { --r; base = r * 99 - ((r * (r - 1)) >> 1); }
    while (p - base >= (99 - r)) { base += (99 - r); ++r; }
    c = r + 1 + (p - base);
}

__global__ void pair_init(unsigned short* __restrict__ tbl) {
    const int p = blockIdx.x * 256 + threadIdx.x;
    if (p < kTblPad) {
        int r, c;
        pair_decode(p < kP ? p : kP - 1, r, c);
        tbl[p] = (unsigned short)((r << 8) | c);
    }
}

// LDS: she 100*40 halfs = 8000 B | sh_pair 4960 u16 = 9920 B (17920 total);
// stg (512*9 floats = 18432 B) aliases the same region after the main loop.
template <bool USE_TBL>
__global__ __launch_bounds__(kNT, 8)
void afm_kernel(const int* __restrict__ x,
                const float* __restrict__ Emb,
                const float* __restrict__ W,    // (32,16)
                const float* __restrict__ bb,   // (16,)
                const float* __restrict__ h,    // (16,)
                const float* __restrict__ W1,   // (32,16)
                const float* __restrict__ b1,   // (16,)
                const float* __restrict__ W2,   // (16,8)
                const float* __restrict__ b2,   // (8,)
                const float* __restrict__ Wf,   // (8,)
                const float* __restrict__ bf,   // (1,)
                const unsigned short* __restrict__ tbl,
                float* __restrict__ out)        // (1024,)
{
    __shared__ __align__(16) unsigned char smem[18432];
    __shared__ float red[8];
    __shared__ float sh_pooled[kD];
    __shared__ float sh_o1[kA];
    __shared__ float sh_o2[8];

    __fp16* she = (__fp16*)smem;
    unsigned short* sh_pair = (unsigned short*)(smem + 8000);

    const int tid  = threadIdx.x;
    const int b    = blockIdx.x;
    const int lane = tid & 63;
    const int wv   = tid >> 6;           // 0..7
    const int quad = lane >> 4;
    const int l15  = lane & 15;
    const int k0   = quad * 8;           // this quad's K slice (dims k0..k0+7)

    // ---- gather embeddings -> f16 LDS ----
    const int* xb = x + b * kT;
    for (int i = tid; i < kT * 8; i += kNT) {
        const int row = i >> 3, c4 = i & 7;
        const int v = xb[row];
        const float4 val = ((const float4*)Emb)[v * 8 + c4];
        union { fp16x2 h2[2]; half4 h4; } tmp;
        tmp.h2[0] = __builtin_amdgcn_cvt_pkrtz(val.x, val.y);
        tmp.h2[1] = __builtin_amdgcn_cvt_pkrtz(val.z, val.w);
        *(half4*)(she + row * kESH + c4 * 4) = tmp.h4;
    }
    // ---- pair table: coalesced load from d_ws, or in-block decode fallback ----
    if (USE_TBL) {
        const uint4* t4 = (const uint4*)tbl;
        for (int i = tid; i < kTblPad / 8; i += kNT)   // 620 uint4
            ((uint4*)sh_pair)[i] = t4[i];
    } else {
        for (int p = tid; p < kP; p += kNT) {
            int r, c;
            pair_decode(p, r, c);
            sh_pair[p] = (unsigned short)((r << 8) | c);
        }
    }

    // ---- A-frag: W^T in f16 (lane holds W[k0+j][a=l15]) + h, bias-C slices ----
    union { fp16x2 h2[4]; half8v h8; } wa;
#pragma unroll
    for (int j = 0; j < 4; ++j)
        wa.h2[j] = __builtin_amdgcn_cvt_pkrtz(W[(k0 + 2 * j) * kA + l15],
                                              W[(k0 + 2 * j + 1) * kA + l15]);
    float h_reg[4];
    float4v bfrag;
#pragma unroll
    for (int rg = 0; rg < 4; ++rg) {
        h_reg[rg] = h[quad * 4 + rg];
        bfrag[rg] = bb[quad * 4 + rg];
    }
    __syncthreads();

    // ---- fused main loop: ~39 tiles per wave ----
    float pool[8];
#pragma unroll
    for (int j = 0; j < 8; ++j) pool[j] = 0.0f;
    float lsum = 0.0f;

#pragma unroll 2
    for (int t = wv; t < kTiles; t += 8) {
        const int p_raw = t * 16 + l15;
        const int p = p_raw < kP ? p_raw : kP - 1;
        const unsigned pr = sh_pair[p];
        const int roff = (int)(pr >> 8) * kESH;
        const int coff = (int)(pr & 255) * kESH;

        const half8 er = *(const half8*)(she + roff + k0);
        const half8 ec = *(const half8*)(she + coff + k0);
        union { half8 fp; half8v mf; } hb;
        hb.fp = er * ec;                       // 4x v_pk_mul_f16

        // C = bias: acc directly holds s = hb@W + b
        float4v acc = __builtin_amdgcn_mfma_f32_16x16x32_f16(wa.h8, hb.mf, bfrag, 0, 0, 0);

        // lane holds s[a=quad*4+rg][p=l15]
        float part = 0.0f;
#pragma unroll
        for (int rg = 0; rg < 4; ++rg)
            part = fmaf(fmaxf(acc[rg], 0.0f), h_reg[rg], part);
        part += __shfl_xor(part, 16, 64);      // full logit in every quad
        part += __shfl_xor(part, 32, 64);

        const float w = (p_raw < kP) ? __expf(part) : 0.0f;
        lsum += w;
#pragma unroll
        for (int j = 0; j < 8; ++j)
            pool[j] = fmaf(w, (float)hb.fp[j], pool[j]);
    }

    // ---- reduce l (quads duplicate w -> x4) ----
#pragma unroll
    for (int off = 1; off < 64; off <<= 1) lsum += __shfl_xor(lsum, off, 64);
    if (lane == 0) red[wv] = lsum;

    __syncthreads();                 // main-loop LDS reads done; smem reusable
    float* stg = (float*)smem;       // 512 * 9 floats = 18432 B
#pragma unroll
    for (int j = 0; j < 8; ++j) stg[tid * 9 + j] = pool[j];
    __syncthreads();

    // pooled[d]: contributors are lanes whose quad == d>>3, all 8 waves
    if (tid < kD) {
        const float invS = 4.0f / (red[0] + red[1] + red[2] + red[3] +
                                   red[4] + red[5] + red[6] + red[7]);
        const int q = tid >> 3, j = tid & 7;
        float s = 0.0f;
        for (int w8 = 0; w8 < 8; ++w8)
            for (int l = 0; l < 16; ++l)
                s += stg[(w8 * 64 + q * 16 + l) * 9 + j];
        sh_pooled[tid] = s * invS;
    }
    __syncthreads();

    // ---- MLP head ----
    if (tid < kA) {
        float o = b1[tid];
#pragma unroll
        for (int d = 0; d < kD; ++d) o = fmaf(sh_pooled[d], W1[d * kA + tid], o);
        sh_o1[tid] = fmaxf(o, 0.0f);
    }
    __syncthreads();
    if (tid < 8) {
        float o = b2[tid];
#pragma unroll
        for (int a = 0; a < kA; ++a) o = fmaf(sh_o1[a], W2[a * 8 + tid], o);
        sh_o2[tid] = fmaxf(o, 0.0f);
    }
    __syncthreads();
    if (tid == 0) {
        float z = bf[0];
#pragma unroll
        for (int j = 0; j < 8; ++j) z = fmaf(sh_o2[j], Wf[j], z);
        out[b] = 1.0f / (1.0f + __expf(-z));
    }
}

extern "C" void kernel_launch(void* const* d_in, const int* in_sizes, int n_in,
                              void* d_out, int out_size, void* d_ws, size_t ws_size,
                              hipStream_t stream) {
    const int*   x   = (const int*)d_in[0];
    const float* Emb = (const float*)d_in[1];
    const float* W   = (const float*)d_in[2];
    const float* bb  = (const float*)d_in[3];
    const float* h   = (const float*)d_in[4];
    const float* W1  = (const float*)d_in[5];
    const float* b1  = (const float*)d_in[6];
    const float* W2  = (const float*)d_in[7];
    const float* b2  = (const float*)d_in[8];
    const float* Wf  = (const float*)d_in[9];
    const float* bf  = (const float*)d_in[10];
    float* out = (float*)d_out;

    if (ws_size >= (size_t)(kTblPad * 2)) {
        unsigned short* tbl = (unsigned short*)d_ws;
        pair_init<<<(kTblPad + 255) / 256, 256, 0, stream>>>(tbl);
        afm_kernel<true><<<1024, kNT, 0, stream>>>(x, Emb, W, bb, h, W1, b1, W2, b2,
                                                   Wf, bf, tbl, out);
    } else {
        afm_kernel<false><<<1024, kNT, 0, stream>>>(x, Emb, W, bb, h, W1, b1, W2, b2,
                                                    Wf, bf, nullptr, out);
    }
}